// Round 1
// baseline (617.879 us; speedup 1.0000x reference)
//
#include <hip/hip_runtime.h>
#include <hip/hip_bf16.h>
#include <stdint.h>

#define NROW 8192
#define DIM  256
#define TILE 128
#define BK   64

typedef unsigned short u16;
typedef __attribute__((ext_vector_type(8))) short short8;
typedef __attribute__((ext_vector_type(4))) float f32x4;

__device__ __forceinline__ void load_lds16(const void* g, void* l) {
    __builtin_amdgcn_global_load_lds(
        (const __attribute__((address_space(1))) void*)g,
        (__attribute__((address_space(3))) void*)l,
        16, 0, 0);
}

// Kernel 1: fp32 -> bf16 (RNE) + per-row sum of squares (x2)
__global__ __launch_bounds__(256) void prep_kernel(const float* __restrict__ emb,
                                                   u16* __restrict__ ebf,
                                                   float* __restrict__ x2) {
    const int row = blockIdx.x;
    const int tid = threadIdx.x;
    float v = emb[(size_t)row * DIM + tid];
    uint32_t bits = __float_as_uint(v);
    uint32_t r = (bits + 0x7FFFu + ((bits >> 16) & 1u)) >> 16;  // round-to-nearest-even
    ebf[(size_t)row * DIM + tid] = (u16)r;
    float s = v * v;
#pragma unroll
    for (int off = 32; off > 0; off >>= 1) s += __shfl_down(s, off, 64);
    __shared__ float ws4[4];
    if ((tid & 63) == 0) ws4[tid >> 6] = s;
    __syncthreads();
    if (tid == 0) x2[row] = ws4[0] + ws4[1] + ws4[2] + ws4[3];
}

// Kernel 2: tiled E*E^T (bf16 MFMA) with fused Poincare epilogue.
// 3 blocks/CU: one block's epilogue store-burst overlaps another's MFMA loop.
__global__ __launch_bounds__(256, 3) void poincare_kernel(const u16* __restrict__ ebf,
                                                          const float* __restrict__ x2,
                                                          float* __restrict__ out) {
    // LDS tiles, [128 rows][64 k-elems] bf16, XOR-swizzled in 16B chunks:
    // slot (row, s) holds global k-chunk (s ^ (row & 7)).
    __shared__ __align__(16) u16 Asm[TILE * BK];
    __shared__ __align__(16) u16 Bsm[TILE * BK];

    const int tid  = threadIdx.x;
    const int wave = tid >> 6;
    const int lane = tid & 63;

    const int brow = blockIdx.x * TILE;
    const int bcol = blockIdx.y * TILE;

    const int wm = (wave & 1) * 64;   // wave row offset inside tile
    const int wn = (wave >> 1) * 64;  // wave col offset inside tile

    f32x4 acc[4][4];
#pragma unroll
    for (int m = 0; m < 4; ++m)
#pragma unroll
        for (int n = 0; n < 4; ++n) acc[m][n] = (f32x4){0.f, 0.f, 0.f, 0.f};

    // staging: lane -> slot (srow = lane>>3, schunk = lane&7); gptr fetches the
    // swizzled logical chunk so the LDS write stays base + lane*16.
    const int srow = lane >> 3;
    const int sc   = (((lane & 7) ^ srow) * 8);  // element offset within row

    const int lcol  = lane & 15;
    const int quad  = lane >> 4;
    const int chbase = quad ^ (lane & 7);        // read-side swizzled chunk, ks=0

    for (int k0 = 0; k0 < DIM; k0 += BK) {
#pragma unroll
        for (int t = 0; t < 4; ++t) {
            const int rr = wave * 32 + t * 8;  // wave-uniform group base row
            const u16* gA = ebf + (size_t)(brow + rr + srow) * DIM + k0 + sc;
            const u16* gB = ebf + (size_t)(bcol + rr + srow) * DIM + k0 + sc;
            load_lds16(gA, &Asm[rr * BK]);
            load_lds16(gB, &Bsm[rr * BK]);
        }
        __syncthreads();

#pragma unroll
        for (int ks = 0; ks < 2; ++ks) {
            const int cc = chbase ^ (ks << 2);
            short8 af[4], bfr[4];
#pragma unroll
            for (int m = 0; m < 4; ++m) {
                const int row = wm + m * 16 + lcol;
                af[m] = *(const short8*)&Asm[row * BK + cc * 8];
            }
#pragma unroll
            for (int n = 0; n < 4; ++n) {
                const int row = wn + n * 16 + lcol;
                bfr[n] = *(const short8*)&Bsm[row * BK + cc * 8];
            }
#pragma unroll
            for (int m = 0; m < 4; ++m)
#pragma unroll
                for (int n = 0; n < 4; ++n)
                    acc[m][n] = __builtin_amdgcn_mfma_f32_16x16x32_bf16(
                        af[m], bfr[n], acc[m][n], 0, 0, 0);
        }
        __syncthreads();
    }

    // ---- Epilogue ----
    // MFMA C/D layout: col = lane&15, row = quad*4 + reg. Transpose each (m,n)
    // 4x4 sub-block across 4-lane groups (2 shfl_xor butterfly stages -> DPP
    // quad_perm) so each lane holds 4 consecutive COLUMNS of one row, enabling
    // nontemporal dwordx4 stores (32 per wave instead of 128 scalar).
    const int j4 = lane & 3;           // index within the 4-lane transpose group
    const int c4 = lane & 12;          // 4-col chunk selector (lcol & 12)

    float* __restrict__ probs = out;
    float* __restrict__ dists = out + (size_t)NROW * NROW;

#pragma unroll
    for (int m = 0; m < 4; ++m) {
        const int grow = brow + wm + m * 16 + quad * 4 + j4;
        const float xi2 = x2[grow];
        const float Bv  = 1.f - xi2;
        const float Bv2 = Bv * Bv;
        const size_t rowoff = (size_t)grow * NROW;
#pragma unroll
        for (int n = 0; n < 4; ++n) {
            float v0 = acc[m][n][0], v1 = acc[m][n][1],
                  v2 = acc[m][n][2], v3 = acc[m][n][3];
            // stage 1 (mask 1): u[r] = ((r^j)&1) ? shfl_xor(v[r^1],1) : v[r]
            const bool s1 = (j4 & 1) != 0;
            float a0 = __shfl_xor(v1, 1);
            float a1 = __shfl_xor(v0, 1);
            float a2 = __shfl_xor(v3, 1);
            float a3 = __shfl_xor(v2, 1);
            float u0 = s1 ? a0 : v0;
            float u1 = s1 ? v1 : a1;
            float u2 = s1 ? a2 : v2;
            float u3 = s1 ? v3 : a3;
            // stage 2 (mask 2): w[r] = ((r^j)&2) ? shfl_xor(u[r^2],2) : u[r]
            const bool s2 = (j4 & 2) != 0;
            float b0 = __shfl_xor(u2, 2);
            float b1 = __shfl_xor(u3, 2);
            float b2 = __shfl_xor(u0, 2);
            float b3 = __shfl_xor(u1, 2);
            float w0 = s2 ? b0 : u0;
            float w1 = s2 ? b1 : u1;
            float w2 = s2 ? u2 : b2;
            float w3 = s2 ? u3 : b3;
            // now lane j4 holds row (quad*4 + j4), cols gcolbase + {0,1,2,3}
            float w[4] = {w0, w1, w2, w3};

            const int gcolbase = bcol + wn + n * 16 + c4;
            const f32x4 xj2v = *(const f32x4*)&x2[gcolbase];
            f32x4 pr, dv;
#pragma unroll
            for (int r = 0; r < 4; ++r) {
                const float dot = w[r];
                const float xj2 = xj2v[r];
                const float Av = 1.f - 2.f * dot + xj2;
                const float Dv = 1.f - 2.f * dot + xi2 * xj2;
                float num2 = Av * Av * xi2 - 2.f * Av * Bv * dot + Bv2 * xj2;
                num2 = fmaxf(num2, 0.f);
                const float den = fmaxf(fabsf(Dv), 1e-15f);
                float s = __builtin_amdgcn_sqrtf(num2);
                s = fminf(s, den * 0.9999999f);      // t = s/den <= 1-1e-7
                const float dm = den - s;
                const float R  = __builtin_amdgcn_rcpf(den * dm);  // 1/(den*(den-s))
                const float t  = s * dm * R;                        // s/den
                float dist = __logf((den + s) * den * R);  // log((1+t)/(1-t))
                float prob = fmaf(-0.5f, t, 0.5f);         // (1-t)/2
                if (grow == gcolbase + r) { dist = 0.f; prob = 0.f; }
                pr[r] = prob;
                dv[r] = dist;
            }
            __builtin_nontemporal_store(pr, (f32x4*)(probs + rowoff + gcolbase));
            __builtin_nontemporal_store(dv, (f32x4*)(dists + rowoff + gcolbase));
        }
    }
}

extern "C" void kernel_launch(void* const* d_in, const int* in_sizes, int n_in,
                              void* d_out, int out_size, void* d_ws, size_t ws_size,
                              hipStream_t stream) {
    (void)in_sizes; (void)n_in; (void)out_size; (void)ws_size;
    const float* emb = (const float*)d_in[0];
    float* out = (float*)d_out;
    u16*   ebf = (u16*)d_ws;
    float* x2  = (float*)((char*)d_ws + (size_t)NROW * DIM * sizeof(u16));

    prep_kernel<<<NROW, 256, 0, stream>>>(emb, ebf, x2);
    dim3 grid(NROW / TILE, NROW / TILE);
    poincare_kernel<<<grid, 256, 0, stream>>>(ebf, x2, out);
}